// Round 4
// baseline (124.824 us; speedup 1.0000x reference)
//
#include <hip/hip_runtime.h>
#include <hip/hip_bf16.h>

// Problem constants (reference: B,H,I,E = 16,16,512,512)
#define B_ 16
#define H_ 16
#define I_ 512
#define E_ 512

// Algebraic collapse (verified rounds 1-3, absmax <= 0.25):
//   softmax(axis=2) followed by sum(axis=2) makes attention exact identity on V:
//   emb[b,h,e] = sum_i x[b,i,e] * W_v[h,i,e];  out = emb @ mlp_w^T + mlp_b.
//
// Round-4 structure: TWO kernels only (fitted model: ~13.7 us overhead per
// dispatch node dominates; 4->2 nodes ~= -27 us).
//   K1: emb partials (NSLICE=8 i-slices) + zeroes `out` for K2's atomics.
//   K2: slice-reduce + GEMM + bias fused; k-split partial tiles combined via
//       global fp32 atomicAdd into the pre-zeroed `out`.

#define NSLICE 8

// ---------------------------------------------------------------------------
// K1: epart[s][b*16+h][e] = sum_{i in slice s} x[b,i,e] * Wv[h,i,e]
// Block: 8b x 8h x 64e, 512 threads = 8 waves, wave w handles 8 i's of the
// block's 64-i slice. Cross-wave reduce via 64 KB LDS in two rounds.
// Grid (8 e-chunks, 2 b-groups, 2 h-groups * 8 slices) = 256 blocks.
// Logical traffic: x*2 + Wv*2 = 64 MB + 4 MB partials.
// Also zeroes out[256][512] (first 64 blocks, one float4/thread).
// ---------------------------------------------------------------------------
__global__ __launch_bounds__(512) void k_emb_part(const float* __restrict__ x,
                                                  const float* __restrict__ Wv,
                                                  float* __restrict__ epart,
                                                  float4* __restrict__ out4) {
    const int e0    = blockIdx.x * 64;
    const int b0    = blockIdx.y * 8;
    const int h0    = (blockIdx.z & 1) * 8;
    const int slice = blockIdx.z >> 1;          // 0..7
    const int lane  = threadIdx.x & 63;
    const int wave  = threadIdx.x >> 6;         // 0..7
    const int e     = e0 + lane;

    // zero `out` for K2's atomicAdd (stream order: K1 completes before K2)
    {
        const int blin = (blockIdx.z * 2 + blockIdx.y) * 8 + blockIdx.x;
        const int gid  = blin * 512 + threadIdx.x;
        if (gid < (B_ * H_ * E_) / 4) {
            float4 z; z.x = 0.f; z.y = 0.f; z.z = 0.f; z.w = 0.f;
            out4[gid] = z;
        }
    }

    float acc[8][8];
#pragma unroll
    for (int bi = 0; bi < 8; ++bi)
#pragma unroll
        for (int hj = 0; hj < 8; ++hj) acc[bi][hj] = 0.0f;

    const int ibase = slice * 64 + wave * 8;
    const float* xp[8];
    const float* wp[8];
#pragma unroll
    for (int bi = 0; bi < 8; ++bi)
        xp[bi] = x + ((size_t)(b0 + bi) * I_ + ibase) * E_ + e;
#pragma unroll
    for (int hj = 0; hj < 8; ++hj)
        wp[hj] = Wv + ((size_t)(h0 + hj) * I_ + ibase) * E_ + e;

#pragma unroll
    for (int ii = 0; ii < 8; ++ii) {
        const int off = ii * E_;
        float xv[8], wv[8];
#pragma unroll
        for (int bi = 0; bi < 8; ++bi) xv[bi] = xp[bi][off];
#pragma unroll
        for (int hj = 0; hj < 8; ++hj) wv[hj] = wp[hj][off];
#pragma unroll
        for (int bi = 0; bi < 8; ++bi)
#pragma unroll
            for (int hj = 0; hj < 8; ++hj)
                acc[bi][hj] = fmaf(xv[bi], wv[hj], acc[bi][hj]);
    }

    // 8-wave reduce in two rounds through 64 KB LDS (stride-1 in lane: free)
    __shared__ float red[4][64][64];
    if (wave >= 4) {
#pragma unroll
        for (int bi = 0; bi < 8; ++bi)
#pragma unroll
            for (int hj = 0; hj < 8; ++hj)
                red[wave - 4][bi * 8 + hj][lane] = acc[bi][hj];
    }
    __syncthreads();
    if (wave < 4) {
#pragma unroll
        for (int bi = 0; bi < 8; ++bi)
#pragma unroll
            for (int hj = 0; hj < 8; ++hj) {
                const int p = bi * 8 + hj;
                red[wave][p][lane] = acc[bi][hj] + red[wave][p][lane];
            }
    }
    __syncthreads();

    // gather 4-way sums, write partial slice (coalesced 256 B rows)
    for (int rep = 0; rep < 8; ++rep) {
        const int o  = rep * 512 + threadIdx.x;
        const int p  = o >> 6, le = o & 63;
        const float s = (red[0][p][le] + red[1][p][le]) +
                        (red[2][p][le] + red[3][p][le]);
        const int row = (b0 + (p >> 3)) * H_ + h0 + (p & 7);
        epart[((size_t)slice * (B_ * H_) + row) * E_ + e0 + le] = s;
    }
}

// ---------------------------------------------------------------------------
// K2: out[r,c] += (sum_s epart[s])[r,:] @ W[c,:] (+ bias by kc==0 blocks)
// Block: 32r x 128c out-tile, 64-k chunk (kc = blockIdx.z). A-tile built by
// summing the 8 epart slices during staging. Both LDS tiles stored [k][*]
// with 16B-aligned pads -> main loop is 2 conflict-free ds_read_b128 per
// 16 fma. Partial tiles combined via atomicAdd (out pre-zeroed by K1).
// Grid (4, 8, 8) = 256 blocks, 256 threads, ~43 KB LDS -> 3 blocks/CU.
// ---------------------------------------------------------------------------
__global__ __launch_bounds__(256) void k_mlp(const float* __restrict__ epart,
                                             const float* __restrict__ W,
                                             const float* __restrict__ bias,
                                             float* __restrict__ out) {
    const int cblk = blockIdx.x;   // 0..3  (128 cols)
    const int rblk = blockIdx.y;   // 0..7  (32 rows)
    const int kc   = blockIdx.z;   // 0..7  (64 k)

    __shared__ float At[64][36];    // [k][r]  9.2 KB (144 B rows: 16B-aligned)
    __shared__ float Wt[64][132];   // [k][c] 33.8 KB (528 B rows: 16B-aligned)

    const int t = threadIdx.x;

    // stage A: sum 8 slices of epart[32r x 64k], store transposed
    {
        const int r = t >> 3, kq = t & 7;   // 8 threads per row, 64 floats/row
        const float* base = epart + (size_t)(rblk * 32 + r) * E_ + kc * 64 + kq * 8;
        float4 a0 = {0, 0, 0, 0}, a1 = {0, 0, 0, 0};
#pragma unroll
        for (int s = 0; s < NSLICE; ++s) {
            const float4* p = (const float4*)(base + (size_t)s * (B_ * H_ * E_));
            float4 v0 = p[0], v1 = p[1];
            a0.x += v0.x; a0.y += v0.y; a0.z += v0.z; a0.w += v0.w;
            a1.x += v1.x; a1.y += v1.y; a1.z += v1.z; a1.w += v1.w;
        }
        const int k = kq * 8;
        At[k + 0][r] = a0.x; At[k + 1][r] = a0.y;
        At[k + 2][r] = a0.z; At[k + 3][r] = a0.w;
        At[k + 4][r] = a1.x; At[k + 5][r] = a1.y;
        At[k + 6][r] = a1.z; At[k + 7][r] = a1.w;
    }
    // stage W: 128c x 64k, float4 along k, store transposed (conflict-free)
    {
        const int wc = t >> 1, half = t & 1;   // 2 threads per row
        const float* src = W + (size_t)(cblk * 128 + wc) * E_ + kc * 64 + half * 32;
#pragma unroll
        for (int j = 0; j < 8; ++j) {
            float4 v = ((const float4*)src)[j];
            const int k = half * 32 + j * 4;
            Wt[k + 0][wc] = v.x; Wt[k + 1][wc] = v.y;
            Wt[k + 2][wc] = v.z; Wt[k + 3][wc] = v.w;
        }
    }
    __syncthreads();

    const int tx = t & 31, ty = t >> 5;   // 32 c-quads x 8 r-quads
    const int c0 = tx * 4, r0 = ty * 4;

    float4 acc[4];
#pragma unroll
    for (int i = 0; i < 4; ++i) { acc[i].x = 0.f; acc[i].y = 0.f; acc[i].z = 0.f; acc[i].w = 0.f; }

#pragma unroll 8
    for (int k = 0; k < 64; ++k) {
        const float4 a = *(const float4*)&At[k][r0];  // 2 addrs/wave: broadcast
        const float4 w = *(const float4*)&Wt[k][c0];  // contiguous b128
        acc[0].x = fmaf(a.x, w.x, acc[0].x); acc[0].y = fmaf(a.x, w.y, acc[0].y);
        acc[0].z = fmaf(a.x, w.z, acc[0].z); acc[0].w = fmaf(a.x, w.w, acc[0].w);
        acc[1].x = fmaf(a.y, w.x, acc[1].x); acc[1].y = fmaf(a.y, w.y, acc[1].y);
        acc[1].z = fmaf(a.y, w.z, acc[1].z); acc[1].w = fmaf(a.y, w.w, acc[1].w);
        acc[2].x = fmaf(a.z, w.x, acc[2].x); acc[2].y = fmaf(a.z, w.y, acc[2].y);
        acc[2].z = fmaf(a.z, w.z, acc[2].z); acc[2].w = fmaf(a.z, w.w, acc[2].w);
        acc[3].x = fmaf(a.w, w.x, acc[3].x); acc[3].y = fmaf(a.w, w.y, acc[3].y);
        acc[3].z = fmaf(a.w, w.z, acc[3].z); acc[3].w = fmaf(a.w, w.w, acc[3].w);
    }

    if (kc == 0) {   // bias added exactly once (deterministic owner)
        const float4 bv = *(const float4*)&bias[cblk * 128 + c0];
#pragma unroll
        for (int i = 0; i < 4; ++i) {
            acc[i].x += bv.x; acc[i].y += bv.y; acc[i].z += bv.z; acc[i].w += bv.w;
        }
    }

#pragma unroll
    for (int i = 0; i < 4; ++i) {
        float* dst = out + (size_t)(rblk * 32 + r0 + i) * E_ + cblk * 128 + c0;
        atomicAdd(dst + 0, acc[i].x);
        atomicAdd(dst + 1, acc[i].y);
        atomicAdd(dst + 2, acc[i].z);
        atomicAdd(dst + 3, acc[i].w);
    }
}

extern "C" void kernel_launch(void* const* d_in, const int* in_sizes, int n_in,
                              void* d_out, int out_size, void* d_ws, size_t ws_size,
                              hipStream_t stream) {
    // setup_inputs order: x, W_q, W_k, W_v, mlp_w, mlp_b  (all fp32)
    const float* x     = (const float*)d_in[0];
    const float* W_v   = (const float*)d_in[3];
    const float* mlp_w = (const float*)d_in[4];
    const float* mlp_b = (const float*)d_in[5];
    float* out = (float*)d_out;

    float* epart = (float*)d_ws;   // 8 slices x 256 x 512 floats = 4 MB

    dim3 g1(E_ / 64, B_ / 8, (H_ / 8) * NSLICE);   // (8,2,16) = 256 blocks
    k_emb_part<<<g1, 512, 0, stream>>>(x, W_v, epart, (float4*)out);

    dim3 g2(E_ / 128, (B_ * H_) / 32, NSLICE);     // (4,8,8) = 256 blocks
    k_mlp<<<g2, 256, 0, stream>>>(epart, mlp_w, mlp_b, out);
}

// Round 6
// 112.882 us; speedup vs baseline: 1.1058x; 1.1058x over previous
//
#include <hip/hip_runtime.h>
#include <hip/hip_bf16.h>

// Problem constants (reference: B,H,I,E = 16,16,512,512)
#define B_ 16
#define H_ 16
#define I_ 512
#define E_ 512

// Algebraic collapse (verified rounds 1-4, absmax <= 0.25):
//   softmax(axis=2) followed by sum(axis=2) makes attention exact identity on V:
//   emb[b,h,e] = sum_i x[b,i,e] * W_v[h,i,e];  out = emb @ mlp_w^T + mlp_b.
//
// Round-6 structure: 3 plain stream kernels (R5 post-mortem: cooperative
// launch silently no-ops under graph capture; R4: atomics into hot 512 KB
// cost ~30 us cross-XCD -> banned).
//   K1: emb partials (NSL=8 i-slices), R4-proven 8b x 8h x 64e blocking.
//   K2: R3-proven k-split GEMM, A-stage fused with the slice reduction.
//   K3: k-reduce + bias (tiny).

#define NSL 8      // i-slices for K1 / slices summed in K2's A-stage
#define KSPLIT 8   // k-split for K2 (64 k's each)

// ---------------------------------------------------------------------------
// K1: epart[s][b*16+h][e] = sum_{i in slice s} x[b,i,e] * Wv[h,i,e]
// Block: 8b x 8h x 64e, 512 threads = 8 waves, wave w handles 8 i's of the
// block's 64-i slice. Cross-wave reduce via 64 KB LDS in two rounds.
// Grid (8 e-chunks, 2 b-groups, 2 h-groups * 8 slices) = 256 blocks.
// Logical traffic: x*2 + Wv*2 = 64 MB (L2/L3-resident) + 4 MB partials.
// ---------------------------------------------------------------------------
__global__ __launch_bounds__(512) void k_emb_part(const float* __restrict__ x,
                                                  const float* __restrict__ Wv,
                                                  float* __restrict__ epart) {
    const int e0    = blockIdx.x * 64;
    const int b0    = blockIdx.y * 8;
    const int h0    = (blockIdx.z & 1) * 8;
    const int slice = blockIdx.z >> 1;          // 0..7
    const int lane  = threadIdx.x & 63;
    const int wave  = threadIdx.x >> 6;         // 0..7
    const int e     = e0 + lane;

    float acc[8][8];
#pragma unroll
    for (int bi = 0; bi < 8; ++bi)
#pragma unroll
        for (int hj = 0; hj < 8; ++hj) acc[bi][hj] = 0.0f;

    const int ibase = slice * 64 + wave * 8;
    const float* xp[8];
    const float* wp[8];
#pragma unroll
    for (int bi = 0; bi < 8; ++bi)
        xp[bi] = x + ((size_t)(b0 + bi) * I_ + ibase) * E_ + e;
#pragma unroll
    for (int hj = 0; hj < 8; ++hj)
        wp[hj] = Wv + ((size_t)(h0 + hj) * I_ + ibase) * E_ + e;

#pragma unroll
    for (int ii = 0; ii < 8; ++ii) {
        const int off = ii * E_;
        float xv[8], wv[8];
#pragma unroll
        for (int bi = 0; bi < 8; ++bi) xv[bi] = xp[bi][off];
#pragma unroll
        for (int hj = 0; hj < 8; ++hj) wv[hj] = wp[hj][off];
#pragma unroll
        for (int bi = 0; bi < 8; ++bi)
#pragma unroll
            for (int hj = 0; hj < 8; ++hj)
                acc[bi][hj] = fmaf(xv[bi], wv[hj], acc[bi][hj]);
    }

    // 8-wave reduce in two rounds through 64 KB LDS (stride-1 in lane: free)
    __shared__ float red[4][64][64];
    if (wave >= 4) {
#pragma unroll
        for (int bi = 0; bi < 8; ++bi)
#pragma unroll
            for (int hj = 0; hj < 8; ++hj)
                red[wave - 4][bi * 8 + hj][lane] = acc[bi][hj];
    }
    __syncthreads();
    if (wave < 4) {
#pragma unroll
        for (int bi = 0; bi < 8; ++bi)
#pragma unroll
            for (int hj = 0; hj < 8; ++hj) {
                const int p = bi * 8 + hj;
                red[wave][p][lane] = acc[bi][hj] + red[wave][p][lane];
            }
    }
    __syncthreads();

    // gather 4-way sums, write partial slice (coalesced 256 B rows)
#pragma unroll
    for (int rep = 0; rep < 8; ++rep) {
        const int o  = rep * 512 + threadIdx.x;
        const int p  = o >> 6, le = o & 63;
        const float s = (red[0][p][le] + red[1][p][le]) +
                        (red[2][p][le] + red[3][p][le]);
        const int row = (b0 + (p >> 3)) * H_ + h0 + (p & 7);
        epart[((size_t)slice * (B_ * H_) + row) * E_ + e0 + le] = s;
    }
}

// ---------------------------------------------------------------------------
// K2: K-split GEMM partials, A built by summing the NSL epart slices.
// out-tile 32r x 64c, k-chunk 64, 4x4 micro. Grid (8,8,8) = 512 blocks,
// 128 threads. As[r][k] pad 68, Ws[k][c] pad 68: main-loop reads are
// conflict-free b128 (A rows 2-way aliased = free). LDS bytes/fma = 2B.
// ---------------------------------------------------------------------------
__global__ __launch_bounds__(128) void k_mlp_part(const float* __restrict__ epart,
                                                  const float* __restrict__ W,
                                                  float* __restrict__ mpart) {
    const int cblk = blockIdx.x;   // 64-col tile
    const int rblk = blockIdx.y;   // 32-row tile
    const int k0   = blockIdx.z * 64;

    __shared__ float As[32][68];   // [r][k]  8.7 KB
    __shared__ float Ws[64][68];   // [k][c] 17.4 KB

    const int t = threadIdx.x;

    // stage A: 32r x 64k = sum of NSL epart slices (fused slice-reduce).
    // All reads are L2/L3-resident float4, b128 LDS stores.
    {
        const int r8 = t >> 4, kq = t & 15;
#pragma unroll
        for (int it = 0; it < 4; ++it) {
            const int r = r8 + it * 8;
            const float* base = epart + (size_t)(rblk * 32 + r) * E_ + k0 + kq * 4;
            float4 a = {0.f, 0.f, 0.f, 0.f};
#pragma unroll
            for (int s = 0; s < NSL; ++s) {
                float4 v = *(const float4*)(base + (size_t)s * (B_ * H_ * E_));
                a.x += v.x; a.y += v.y; a.z += v.z; a.w += v.w;
            }
            *(float4*)&As[r][kq * 4] = a;
        }
    }
    // stage W: 64c x 64k, float4 along k (coalesced), transposed scalar
    // stores (small conflict accepted: 32 instrs/thread)
    {
        const int c8 = t >> 4, kq = t & 15;
#pragma unroll
        for (int it = 0; it < 8; ++it) {
            const int c = c8 + it * 8;
            float4 v = *(const float4*)(W + (size_t)(cblk * 64 + c) * E_ + k0 + kq * 4);
            Ws[kq * 4 + 0][c] = v.x;
            Ws[kq * 4 + 1][c] = v.y;
            Ws[kq * 4 + 2][c] = v.z;
            Ws[kq * 4 + 3][c] = v.w;
        }
    }
    __syncthreads();

    const int tx = t & 15, ty = t >> 4;   // c-quad 0..15, r-quad 0..7
    const int c0 = tx * 4, r0 = ty * 4;

    float4 acc0 = {0, 0, 0, 0}, acc1 = {0, 0, 0, 0};
    float4 acc2 = {0, 0, 0, 0}, acc3 = {0, 0, 0, 0};

    for (int k = 0; k < 64; k += 4) {
        float4 a0 = *(const float4*)&As[r0 + 0][k];
        float4 a1 = *(const float4*)&As[r0 + 1][k];
        float4 a2 = *(const float4*)&As[r0 + 2][k];
        float4 a3 = *(const float4*)&As[r0 + 3][k];
        float4 w0 = *(const float4*)&Ws[k + 0][c0];
        float4 w1 = *(const float4*)&Ws[k + 1][c0];
        float4 w2 = *(const float4*)&Ws[k + 2][c0];
        float4 w3 = *(const float4*)&Ws[k + 3][c0];
#define MLP_STEP(ACC, AV)                                                  \
        ACC.x = fmaf(AV.x, w0.x, fmaf(AV.y, w1.x, fmaf(AV.z, w2.x, fmaf(AV.w, w3.x, ACC.x)))); \
        ACC.y = fmaf(AV.x, w0.y, fmaf(AV.y, w1.y, fmaf(AV.z, w2.y, fmaf(AV.w, w3.y, ACC.y)))); \
        ACC.z = fmaf(AV.x, w0.z, fmaf(AV.y, w1.z, fmaf(AV.z, w2.z, fmaf(AV.w, w3.z, ACC.z)))); \
        ACC.w = fmaf(AV.x, w0.w, fmaf(AV.y, w1.w, fmaf(AV.z, w2.w, fmaf(AV.w, w3.w, ACC.w))));
        MLP_STEP(acc0, a0)
        MLP_STEP(acc1, a1)
        MLP_STEP(acc2, a2)
        MLP_STEP(acc3, a3)
#undef MLP_STEP
    }

    float* dst = mpart + ((size_t)blockIdx.z * (B_ * H_) + rblk * 32 + r0) * E_ +
                 cblk * 64 + c0;
    *(float4*)(dst + 0 * E_) = acc0;
    *(float4*)(dst + 1 * E_) = acc1;
    *(float4*)(dst + 2 * E_) = acc2;
    *(float4*)(dst + 3 * E_) = acc3;
}

// ---------------------------------------------------------------------------
// K3: out = sum of KSPLIT partials + bias. 128 blocks x 256 threads.
// ---------------------------------------------------------------------------
__global__ __launch_bounds__(256) void k_out(const float4* __restrict__ part,
                                             const float4* __restrict__ bias,
                                             float4* __restrict__ out) {
    const int idx = blockIdx.x * 256 + threadIdx.x;   // < 32768
    const int sl  = (B_ * H_ * E_) / 4;
    float4 s = part[idx];
#pragma unroll
    for (int j = 1; j < KSPLIT; ++j) {
        float4 p = part[(size_t)j * sl + idx];
        s.x += p.x; s.y += p.y; s.z += p.z; s.w += p.w;
    }
    float4 bv = bias[idx & (E_ / 4 - 1)];
    s.x += bv.x; s.y += bv.y; s.z += bv.z; s.w += bv.w;
    out[idx] = s;
}

extern "C" void kernel_launch(void* const* d_in, const int* in_sizes, int n_in,
                              void* d_out, int out_size, void* d_ws, size_t ws_size,
                              hipStream_t stream) {
    // setup_inputs order: x, W_q, W_k, W_v, mlp_w, mlp_b  (all fp32)
    const float* x     = (const float*)d_in[0];
    const float* W_v   = (const float*)d_in[3];
    const float* mlp_w = (const float*)d_in[4];
    const float* mlp_b = (const float*)d_in[5];
    float* out = (float*)d_out;

    // ws layout: epart (8 x 256 x 512 = 4 MB) | mpart (8 x 256 x 512 = 4 MB)
    float* epart = (float*)d_ws;
    float* mpart = epart + (size_t)NSL * B_ * H_ * E_;

    dim3 g1(E_ / 64, B_ / 8, (H_ / 8) * NSL);   // (8,2,16) = 256 blocks
    k_emb_part<<<g1, 512, 0, stream>>>(x, W_v, epart);

    dim3 g2(E_ / 64, (B_ * H_) / 32, KSPLIT);   // (8,8,8) = 512 blocks
    k_mlp_part<<<g2, 128, 0, stream>>>(epart, mlp_w, mpart);

    k_out<<<(B_ * H_ * E_ / 4) / 256, 256, 0, stream>>>(
        (const float4*)mpart, (const float4*)mlp_b, (float4*)out);
}